// Round 15
// baseline (568.076 us; speedup 1.0000x reference)
//
#include <hip/hip_runtime.h>
#include <math.h>

// ---------------------------------------------------------------------------
// VQ-VAE forward, bf16x3-MFMA for conv2, convT2 AND VQ distances.
//  x (32,1,256,256) -> h_pk (u32 hi|lo) -> z (f32) -> VQ -> q_pk (u32 hi|lo)
//  -> g (f32, aliases h_pk) -> x_recon (32,1,256,256)
// d_out: [0]=vq_loss, [1..131072]=idx (as float), [131073..]=x_recon
// Fragment conventions (HW-verified, absmax 0.0 rounds 4-14):
//   A/B: lane l holds k_local = 8*(l>>4)+j, m/n = l&15
//   C/D: row = (l>>4)*4 + reg, col = l&15
// Round 15: conv2 gets the dconv2 round-14 cure — 2 y-rows/block, 512 thr =
// 8 waves (Yloc x mt), 6 shared staged rows (25.5KB LDS): FETCH -25%,
// barriers/output halved. Per-wave math identical to round-8 (absmax 0.0).
// ---------------------------------------------------------------------------

#define REC_OFF 131073

typedef unsigned short ushort_t;
typedef __attribute__((ext_vector_type(8))) short bf16x8;
typedef __attribute__((ext_vector_type(4))) float f32x4;
typedef __attribute__((ext_vector_type(4))) unsigned int u32x4;
union FragU { u32x4 u; bf16x8 h; };

__device__ __forceinline__ unsigned pack_hilo(float v) {
  unsigned u = __float_as_uint(v);
  unsigned htop = u & 0xFFFF0000u;
  float rf = v - __uint_as_float(htop);
  return htop | (__float_as_uint(rf) >> 16);
}

__global__ __launch_bounds__(64) void zero_loss_k(float* __restrict__ out) {
  if (threadIdx.x == 0) out[0] = 0.f;
}

// ---- conv2 A-table: [ks=ci0*4+ky][mt][lane][j] bf16 hi/lo -----------------
__global__ __launch_bounds__(256) void repackA2_k(
    const float* __restrict__ ew2,
    ushort_t* __restrict__ hi, ushort_t* __restrict__ lo) {
  int idx = blockIdx.x * 256 + threadIdx.x;        // 131072 total
  int j = idx & 7, l = (idx >> 3) & 63, mt = (idx >> 9) & 3, ks = idx >> 11;
  int ci = ((ks >> 2) << 3) + ((l >> 4) << 1) + (j >> 2);
  int ky = ks & 3, kx = j & 3, d = (mt << 4) + (l & 15);
  float val = ew2[((d << 7) + ci) * 16 + (ky << 2) + kx];
  unsigned u = __float_as_uint(val);
  float rf = val - __uint_as_float(u & 0xFFFF0000u);
  hi[idx] = (ushort_t)(u >> 16);
  lo[idx] = (ushort_t)(__float_as_uint(rf) >> 16);
}

// ---- dconv2 A-table (proven) ----------------------------------------------
__global__ __launch_bounds__(256) void repackA_k(
    const float* __restrict__ dw2,   // dec_w2 (ci=64, co=128, ky, kx)
    ushort_t* __restrict__ hi, ushort_t* __restrict__ lo) {
  int idx = blockIdx.x * 256 + threadIdx.x;        // 131072 total
  int j = idx & 7, l = (idx >> 3) & 63, mt = (idx >> 9) & 7;
  int s = (idx >> 12) & 7, v = idx >> 15;
  int co = (mt << 4) + (l & 15);
  int ci = (s << 3) + ((l >> 4) << 1) + (j >> 2);
  int tap = j & 3;
  int Yp = v >> 1, pX = v & 1;
  int kyA = 1 - Yp, kyB = kyA + 2;
  int kxA = pX ? 0 : 1, kxB = kxA + 2;
  int ky = (tap & 2) ? kyB : kyA;
  int kx = (tap & 1) ? kxA : kxB;
  float val = dw2[(((ci << 7) + co) << 4) + (ky << 2) + kx];
  unsigned u = __float_as_uint(val);
  float rf = val - __uint_as_float(u & 0xFFFF0000u);
  hi[idx] = (ushort_t)(u >> 16);
  lo[idx] = (ushort_t)(__float_as_uint(rf) >> 16);
}

// ---- VQ codebook A-table: [ks(2)][mt(32)][lane(64)][j(8)] bf16 hi/lo ------
__global__ __launch_bounds__(256) void repackCB_k(
    const float* __restrict__ cb,
    ushort_t* __restrict__ hi, ushort_t* __restrict__ lo) {
  int idx = blockIdx.x * 256 + threadIdx.x;        // 32768 total
  int j = idx & 7, l = (idx >> 3) & 63, mt = (idx >> 9) & 31, ks = idx >> 14;
  int code = (mt << 4) + (l & 15);
  int k = (ks << 5) + ((l >> 4) << 3) + j;
  float val = cb[(code << 6) + k];
  unsigned u = __float_as_uint(val);
  float rf = val - __uint_as_float(u & 0xFFFF0000u);
  hi[idx] = (ushort_t)(u >> 16);
  lo[idx] = (ushort_t)(__float_as_uint(rf) >> 16);
}

// ---- csq in C/D fragment order: csqF[(mt*64+l)*4+r] = |cb[code]|^2 --------
__global__ __launch_bounds__(256) void csqF_k(
    const float* __restrict__ cb, float* __restrict__ csqF) {
  int idx = blockIdx.x * 256 + threadIdx.x;        // 8192 total
  int r = idx & 3, l = (idx >> 2) & 63, mt = idx >> 8;
  int code = (mt << 4) + ((l >> 4) << 2) + r;
  const float* cp = cb + (code << 6);
  float s = 0.f;
#pragma unroll
  for (int d = 0; d < 64; ++d) s = fmaf(cp[d], cp[d], s);
  csqF[idx] = s;
}

// ---------------- conv1 (1->128, 4x4, s2, p1) + relu -> packed u32 ----------
__global__ __launch_bounds__(128) void conv1_k(
    const float* __restrict__ x, const float* __restrict__ w1,
    const float* __restrict__ b1, unsigned* __restrict__ hp) {
  int oy = blockIdx.x, b = blockIdx.y, ox = threadIdx.x;
  float xv[16];
#pragma unroll
  for (int ky = 0; ky < 4; ++ky) {
    int iy = 2 * oy - 1 + ky;
#pragma unroll
    for (int kx = 0; kx < 4; ++kx) {
      int ix = 2 * ox - 1 + kx;
      float v = 0.f;
      if (iy >= 0 && iy < 256 && ix >= 0 && ix < 256)
        v = x[(b * 256 + iy) * 256 + ix];
      xv[ky * 4 + kx] = v;
    }
  }
  for (int c = 0; c < 128; ++c) {
    const float* wp = w1 + c * 16;                 // wave-uniform -> s_load
    float acc = b1[c];
#pragma unroll
    for (int k = 0; k < 16; ++k) acc = fmaf(xv[k], wp[k], acc);
    hp[((b * 128 + c) * 128 + oy) * 128 + ox] = pack_hilo(fmaxf(acc, 0.f));
  }
}

// ---------------- conv2 (128->64, 4x4, s2, p1) + relu: bf16x3 MFMA ----------
// 2 y-rows/block, 512 thr = 8 waves (Yloc=w>>2, mt=w&3). 6 shared staged
// rows (y = 4a-1 .. 4a+4); LDS row for tap ky of output Yloc = 2*Yloc+ky.
// Per-wave math identical to round-8 form (proven absmax 0.0).
#define C2RL 133
__global__ __launch_bounds__(512) void conv2_k(
    const unsigned* __restrict__ hp, const ushort_t* __restrict__ wCh,
    const ushort_t* __restrict__ wCl, const float* __restrict__ b2,
    float* __restrict__ z) {
  __shared__ unsigned hs[8][6][C2RL];              // 25.5 KB
  int a = blockIdx.x, b = blockIdx.y;              // outputs y = 2a, 2a+1
  int t = threadIdx.x, l = t & 63;
  int w = __builtin_amdgcn_readfirstlane(t >> 6);  // 0..7
  int Yloc = w >> 2, mt = w & 3;
  int y = 2 * a + Yloc;
  int g = l >> 4;

  if (t < 48) {                                    // x-halo prezero
    int ci = t & 7, r = t >> 3;                    // r in 0..5
    hs[ci][r][0] = 0u;
    hs[ci][r][129] = 0u;
  }

  // staging coords: 1536 u32x4/round, thread does 3 (r = r0, r0+2, r0+4)
  int c4 = t & 31, ci_l = (t >> 5) & 7, r0 = t >> 8;   // r0 in {0,1}
  int yr[3];
  bool rowok[3];
#pragma unroll
  for (int i = 0; i < 3; ++i) {
    yr[i] = 4 * a - 1 + r0 + 2 * i;
    rowok[i] = yr[i] >= 0 && yr[i] < 128;
  }
  const unsigned* hbase = hp + (((long)b * 128) << 14);

  u32x4 pre[3];
#pragma unroll
  for (int i = 0; i < 3; ++i)
    pre[i] = rowok[i]
        ? *reinterpret_cast<const u32x4*>(
              hbase + (((long)ci_l << 14) + (yr[i] << 7)) + (c4 << 2))
        : (u32x4)0u;

  f32x4 acc[4];
#pragma unroll
  for (int nt = 0; nt < 4; ++nt) acc[nt] = (f32x4)0.f;

  for (int rnd = 0; rnd < 16; ++rnd) {
    __syncthreads();                               // buffer consumed / halo done
#pragma unroll
    for (int i = 0; i < 3; ++i) {
      unsigned* dst = &hs[ci_l][r0 + 2 * i][1 + (c4 << 2)];
      dst[0] = pre[i][0]; dst[1] = pre[i][1];
      dst[2] = pre[i][2]; dst[3] = pre[i][3];
    }
    __syncthreads();                               // tile visible
    if (rnd < 15) {
      long cb8 = ((long)((rnd + 1) * 8 + ci_l)) << 14;
#pragma unroll
      for (int i = 0; i < 3; ++i)
        pre[i] = rowok[i]
            ? *reinterpret_cast<const u32x4*>(
                  hbase + cb8 + (yr[i] << 7) + (c4 << 2))
            : (u32x4)0u;
    }
#pragma unroll
    for (int ky = 0; ky < 4; ++ky) {
      int ks = (rnd << 2) + ky;
      int row = 2 * Yloc + ky;                     // LDS row 0..5
      FragU ah, al_;
      long aoff = (((long)ks * 4 + mt) * 64 + l) * 8;
      ah.u = *reinterpret_cast<const u32x4*>(wCh + aoff);
      al_.u = *reinterpret_cast<const u32x4*>(wCl + aoff);
#pragma unroll
      for (int nt = 0; nt < 4; ++nt) {
        const unsigned* pa = &hs[g * 2][row][(nt << 5) + 2 * (l & 15)];
        const unsigned* pb = &hs[g * 2 + 1][row][(nt << 5) + 2 * (l & 15)];
        unsigned a0 = pa[0], a1 = pa[1], a2 = pa[2], a3 = pa[3];
        unsigned b0 = pb[0], b1 = pb[1], b2_ = pb[2], b3 = pb[3];
        FragU bh, bl;
        bh.u[0] = __builtin_amdgcn_perm(a1, a0, 0x07060302u);
        bl.u[0] = __builtin_amdgcn_perm(a1, a0, 0x05040100u);
        bh.u[1] = __builtin_amdgcn_perm(a3, a2, 0x07060302u);
        bl.u[1] = __builtin_amdgcn_perm(a3, a2, 0x05040100u);
        bh.u[2] = __builtin_amdgcn_perm(b1, b0, 0x07060302u);
        bl.u[2] = __builtin_amdgcn_perm(b1, b0, 0x05040100u);
        bh.u[3] = __builtin_amdgcn_perm(b3, b2_, 0x07060302u);
        bl.u[3] = __builtin_amdgcn_perm(b3, b2_, 0x05040100u);
        acc[nt] = __builtin_amdgcn_mfma_f32_16x16x32_bf16(
            ah.h, bh.h, acc[nt], 0, 0, 0);
        acc[nt] = __builtin_amdgcn_mfma_f32_16x16x32_bf16(
            ah.h, bl.h, acc[nt], 0, 0, 0);
        acc[nt] = __builtin_amdgcn_mfma_f32_16x16x32_bf16(
            al_.h, bh.h, acc[nt], 0, 0, 0);
      }
    }
  }
#pragma unroll
  for (int nt = 0; nt < 4; ++nt) {
#pragma unroll
    for (int r = 0; r < 4; ++r) {
      int d = (mt << 4) + (g << 2) + r;
      int x = (nt << 4) + (l & 15);
      float v = fmaxf(acc[nt][r] + b2[d], 0.f);
      z[((b * 64 + d) * 64 + y) * 64 + x] = v;
    }
  }
}

// ---------------- VQ: bf16x3 MFMA distances + fp32 argmin (chunked) ---------
__global__ __launch_bounds__(256) void vq_k(
    const float* z, const float* __restrict__ cb,
    const ushort_t* __restrict__ cbFh, const ushort_t* __restrict__ cbFl,
    const float* __restrict__ csqF, unsigned int* q_pk,
    float* __restrict__ out, int n0) {
  __shared__ unsigned zS[64 * 67];                 // 17.2 KB
  __shared__ int bk_arr[64];
  __shared__ float redl[4];
  int t = threadIdx.x, l = t & 63;
  int w = __builtin_amdgcn_readfirstlane(t >> 6);
  int nbase = blockIdx.x * 64;
  int b = nbase >> 12, y = (nbase >> 6) & 63;
  long zbase = (long)b * 262144 + y * 64;

  float zv[16];
#pragma unroll
  for (int j = 0; j < 16; ++j) {
    zv[j] = z[zbase + (long)((w << 4) + j) * 4096 + l];
    zS[l * 67 + (w << 4) + j] = pack_hilo(zv[j]);
  }
  __syncthreads();

  int pp = (w << 4) + (l & 15);
  FragU bh[2], bl[2];
#pragma unroll
  for (int ks = 0; ks < 2; ++ks) {
    const unsigned* zp = &zS[pp * 67 + (ks << 5) + ((l >> 4) << 3)];
    unsigned u0 = zp[0], u1 = zp[1], u2 = zp[2], u3 = zp[3];
    unsigned u4 = zp[4], u5 = zp[5], u6 = zp[6], u7 = zp[7];
    bh[ks].u[0] = __builtin_amdgcn_perm(u1, u0, 0x07060302u);
    bl[ks].u[0] = __builtin_amdgcn_perm(u1, u0, 0x05040100u);
    bh[ks].u[1] = __builtin_amdgcn_perm(u3, u2, 0x07060302u);
    bl[ks].u[1] = __builtin_amdgcn_perm(u3, u2, 0x05040100u);
    bh[ks].u[2] = __builtin_amdgcn_perm(u5, u4, 0x07060302u);
    bl[ks].u[2] = __builtin_amdgcn_perm(u5, u4, 0x05040100u);
    bh[ks].u[3] = __builtin_amdgcn_perm(u7, u6, 0x07060302u);
    bl[ks].u[3] = __builtin_amdgcn_perm(u7, u6, 0x05040100u);
  }

  int g = l >> 4;
  float bd = 1e30f;
  int bk = 0;
  for (int mc = 0; mc < 4; ++mc) {                 // 128 codes per chunk
    f32x4 acc[8];
#pragma unroll
    for (int m8 = 0; m8 < 8; ++m8) acc[m8] = (f32x4)0.f;
#pragma unroll
    for (int ks = 0; ks < 2; ++ks) {
#pragma unroll
      for (int m8 = 0; m8 < 8; ++m8) {
        long aoff = (((long)(ks * 32 + mc * 8 + m8) * 64) + l) * 8;
        FragU ah, al_;
        ah.u = *reinterpret_cast<const u32x4*>(cbFh + aoff);
        al_.u = *reinterpret_cast<const u32x4*>(cbFl + aoff);
        acc[m8] = __builtin_amdgcn_mfma_f32_16x16x32_bf16(
            ah.h, bh[ks].h, acc[m8], 0, 0, 0);
        acc[m8] = __builtin_amdgcn_mfma_f32_16x16x32_bf16(
            ah.h, bl[ks].h, acc[m8], 0, 0, 0);
        acc[m8] = __builtin_amdgcn_mfma_f32_16x16x32_bf16(
            al_.h, bh[ks].h, acc[m8], 0, 0, 0);
      }
    }
#pragma unroll
    for (int m8 = 0; m8 < 8; ++m8) {
      int mt = mc * 8 + m8;
      f32x4 cq = *reinterpret_cast<const f32x4*>(csqF + ((mt << 6) + l) * 4);
#pragma unroll
      for (int r = 0; r < 4; ++r) {
        float d = fmaf(-2.f, acc[m8][r], cq[r]);
        if (d < bd) { bd = d; bk = (mt << 4) + (g << 2) + r; }
      }
    }
  }
#pragma unroll
  for (int m = 16; m <= 32; m <<= 1) {
    float d2 = __shfl_xor(bd, m);
    int k2 = __shfl_xor(bk, m);
    if (d2 < bd || (d2 == bd && k2 < bk)) { bd = d2; bk = k2; }
  }
  if (l < 16) {
    bk_arr[(w << 4) + l] = bk;
    out[1 + n0 + nbase + (w << 4) + l] = (float)bk;
  }
  __syncthreads();

  int bkp = bk_arr[l];
  const float* cbest = cb + (bkp << 6) + (w << 4);
  float ls = 0.f;
#pragma unroll
  for (int j = 0; j < 16; ++j) {
    float c = cbest[j];
    q_pk[zbase + (long)((w << 4) + j) * 4096 + l] = pack_hilo(c);
    float df = c - zv[j];
    ls = fmaf(df, df, ls);
  }
#pragma unroll
  for (int m = 32; m; m >>= 1) ls += __shfl_xor(ls, m);
  if (l == 0) redl[w] = ls;
  __syncthreads();
  if (t == 0)
    atomicAdd(out, (redl[0] + redl[1] + redl[2] + redl[3]) * (1.25f / 8388608.f));
}

// ---------------- convT2 (64->128, 4x4, s2, p1) + relu: bf16x3 MFMA ---------
// 2 Y-rows per block, 512 thr = 8 waves (proven round 14).
__global__ __launch_bounds__(512) void dconv2_k(
    const unsigned int* __restrict__ q_pk, const ushort_t* __restrict__ wAh,
    const ushort_t* __restrict__ wAl, const float* __restrict__ db2,
    float* __restrict__ g) {
  __shared__ unsigned int rows[64][3][68];         // 52,224 B
  int a = blockIdx.x, b = blockIdx.y;              // Y0 = 2a
  int t = threadIdx.x, l = t & 63;
  int w = __builtin_amdgcn_readfirstlane(t >> 6);  // 0..7
  int Yloc = w >> 2, pX = w & 1, coh = (w >> 1) & 1;
  int Y = 2 * a + Yloc;
  int v = (Yloc << 1) | pX;                        // = ((Y&1)<<1)|pX
  int rA = Yloc + 1, rB = Yloc;                    // LDS row idx: yA, yB

  if (t < 192) {
    int ci = t & 63, r = t >> 6;
    rows[ci][r][0] = 0u;
    rows[ci][r][65] = 0u;
  }
  long qb = (long)b * 262144;
#pragma unroll
  for (int r = 0; r < 3; ++r) {
    int yr = a - 1 + r;
    bool ok = (yr >= 0) && (yr < 64);
    for (int s = t; s < 1024; s += 512) {          // 2 iters
      int ci = s >> 4, c4 = s & 15;
      u32x4 val = ok ? *reinterpret_cast<const u32x4*>(
                           q_pk + qb + ci * 4096 + yr * 64 + (c4 << 2))
                     : (u32x4)0u;
      unsigned* dst = &rows[ci][r][1 + (c4 << 2)];
      dst[0] = val[0]; dst[1] = val[1]; dst[2] = val[2]; dst[3] = val[3];
    }
  }
  __syncthreads();

  f32x4 acc[4][4];
#pragma unroll
  for (int mt = 0; mt < 4; ++mt)
#pragma unroll
    for (int nt = 0; nt < 4; ++nt) acc[mt][nt] = (f32x4)0.f;

  for (int s8 = 0; s8 < 8; ++s8) {
    FragU ah[4], al[4];
#pragma unroll
    for (int mt = 0; mt < 4; ++mt) {
      long off = ((((long)(v * 8 + s8) * 8 + (coh * 4 + mt)) * 64 + l) * 8);
      ah[mt].u = *reinterpret_cast<const u32x4*>(wAh + off);
      al[mt].u = *reinterpret_cast<const u32x4*>(wAl + off);
    }
#pragma unroll
    for (int nt = 0; nt < 4; ++nt) {
      int p = nt * 16 + (l & 15) + pX;
      int cc0 = (s8 << 3) + ((l >> 4) << 1);
      unsigned u0 = rows[cc0][rA][p], u1 = rows[cc0][rA][p + 1];
      unsigned u2 = rows[cc0][rB][p], u3 = rows[cc0][rB][p + 1];
      unsigned u4 = rows[cc0 + 1][rA][p], u5 = rows[cc0 + 1][rA][p + 1];
      unsigned u6 = rows[cc0 + 1][rB][p], u7 = rows[cc0 + 1][rB][p + 1];
      FragU bh, bl;
      bh.u[0] = (u0 >> 16) | (u1 & 0xFFFF0000u);
      bl.u[0] = (u0 & 0xFFFFu) | (u1 << 16);
      bh.u[1] = (u2 >> 16) | (u3 & 0xFFFF0000u);
      bl.u[1] = (u2 & 0xFFFFu) | (u3 << 16);
      bh.u[2] = (u4 >> 16) | (u5 & 0xFFFF0000u);
      bl.u[2] = (u4 & 0xFFFFu) | (u5 << 16);
      bh.u[3] = (u6 >> 16) | (u7 & 0xFFFF0000u);
      bl.u[3] = (u6 & 0xFFFFu) | (u7 << 16);
#pragma unroll
      for (int mt = 0; mt < 4; ++mt) {
        acc[mt][nt] = __builtin_amdgcn_mfma_f32_16x16x32_bf16(
            ah[mt].h, bh.h, acc[mt][nt], 0, 0, 0);
        acc[mt][nt] = __builtin_amdgcn_mfma_f32_16x16x32_bf16(
            ah[mt].h, bl.h, acc[mt][nt], 0, 0, 0);
        acc[mt][nt] = __builtin_amdgcn_mfma_f32_16x16x32_bf16(
            al[mt].h, bh.h, acc[mt][nt], 0, 0, 0);
      }
    }
  }

#pragma unroll
  for (int mt = 0; mt < 4; ++mt) {
#pragma unroll
    for (int r = 0; r < 4; ++r) {
      int co = ((coh * 4 + mt) << 4) + ((l >> 4) << 2) + r;
      float bias = db2[co];
#pragma unroll
      for (int nt = 0; nt < 4; ++nt) {
        int X = ((nt << 4) + (l & 15)) * 2 + pX;
        float val = fmaxf(acc[mt][nt][r] + bias, 0.f);
        g[((b * 128 + co) * 128 + Y) * 128 + X] = val;
      }
    }
  }
}

// ---------------- convT1 (128->1, 4x4, s2, p1) + sigmoid --------------------
__global__ __launch_bounds__(256) void dconv1_k(
    const float* __restrict__ g, const float* __restrict__ wd1,
    const float* __restrict__ db1, float* __restrict__ rec) {
  int a2 = blockIdx.x, b = blockIdx.y;
  int t = threadIdx.x;
  int w = __builtin_amdgcn_readfirstlane(t >> 6);
  int l = t & 63;
  int xh = w >> 1, pX = w & 1;
  int L = xh * 64 + l;                       // X = 2L + pX
  int kxA = pX ? 0 : 1, kxB = kxA + 2;
  int ixH = L + pX, ixL = L + pX - 1;
  bool okH = ixH < 128, okL = ixL >= 0;
  int yy0 = 2 * a2 - 1;
  bool vy[4];
#pragma unroll
  for (int r = 0; r < 4; ++r) vy[r] = (yy0 + r) >= 0 && (yy0 + r) < 128;

  const float* gb = g + ((long)b * 128) * 16384 + (long)yy0 * 128;
  float acc[4] = {0.f, 0.f, 0.f, 0.f};

  for (int ci = 0; ci < 128; ci += 2) {
    const float* p0 = gb + (long)ci * 16384;
    const float* p1 = p0 + 16384;
    float hi0[4], lo0[4], hi1[4], lo1[4];
#pragma unroll
    for (int r = 0; r < 4; ++r) {
      const float* q0 = p0 + r * 128;
      const float* q1 = p1 + r * 128;
      hi0[r] = (vy[r] && okH) ? q0[ixH] : 0.f;
      lo0[r] = (vy[r] && okL) ? q0[ixL] : 0.f;
      hi1[r] = (vy[r] && okH) ? q1[ixH] : 0.f;
      lo1[r] = (vy[r] && okL) ? q1[ixL] : 0.f;
    }
    const float* wp0 = wd1 + ci * 16;        // wave-uniform -> s_load
    const float* wp1 = wp0 + 16;
#pragma unroll
    for (int j = 0; j < 4; ++j) {
      int kyA = (j + 1) & 1, kyB = kyA + 2;
      int rA = ((j + 1) >> 1) + 1;           // in [1,3]
      float v = acc[j];
      v = fmaf(wp0[kyA * 4 + kxA], hi0[rA], v);
      v = fmaf(wp0[kyA * 4 + kxB], lo0[rA], v);
      v = fmaf(wp0[kyB * 4 + kxA], hi0[rA - 1], v);
      v = fmaf(wp0[kyB * 4 + kxB], lo0[rA - 1], v);
      v = fmaf(wp1[kyA * 4 + kxA], hi1[rA], v);
      v = fmaf(wp1[kyA * 4 + kxB], lo1[rA], v);
      v = fmaf(wp1[kyB * 4 + kxA], hi1[rA - 1], v);
      v = fmaf(wp1[kyB * 4 + kxB], lo1[rA - 1], v);
      acc[j] = v;
    }
  }
  float bb = db1[0];
#pragma unroll
  for (int j = 0; j < 4; ++j) {
    float v = acc[j] + bb;
    v = 1.f / (1.f + __expf(-v));
    rec[((b * 256 + 4 * a2 + j) * 256) + 2 * L + pX] = v;
  }
}

// ---------------------------------------------------------------------------
extern "C" void kernel_launch(void* const* d_in, const int* in_sizes, int n_in,
                              void* d_out, int out_size, void* d_ws, size_t ws_size,
                              hipStream_t stream) {
  const float* x      = (const float*)d_in[0];
  const float* enc_w1 = (const float*)d_in[1];
  const float* enc_b1 = (const float*)d_in[2];
  const float* enc_w2 = (const float*)d_in[3];
  const float* enc_b2 = (const float*)d_in[4];
  const float* cb     = (const float*)d_in[5];
  const float* dec_w2 = (const float*)d_in[6];
  const float* dec_b2 = (const float*)d_in[7];
  const float* dec_w1 = (const float*)d_in[8];
  const float* dec_b1 = (const float*)d_in[9];

  float* out = (float*)d_out;
  float* ws  = (float*)d_ws;
  ushort_t* wCh  = (ushort_t*)ws;                   // 131072 ushort = 65536 f
  ushort_t* wCl  = (ushort_t*)(ws + 65536);
  ushort_t* wAh  = (ushort_t*)(ws + 131072);
  ushort_t* wAl  = (ushort_t*)(ws + 196608);
  ushort_t* cbFh = (ushort_t*)(ws + 262144);        // 32768 ushort = 16384 f
  ushort_t* cbFl = (ushort_t*)(ws + 278528);
  float* csqF = ws + 294912;                        // 8192 f
  float* dyn  = ws + 303104;                        // chunk buffers

  // Per-image: h_pk = 2,097,152 u32 (g f32 aliases), z/q_pk = 262,144.
  const size_t PER_IMG = 2097152 + 262144;                   // 2,359,296 elems
  size_t avail = (ws_size / 4 > 303104 + 64) ? ws_size / 4 - 303104 - 64 : 0;
  int CB = 32;
  while (CB > 1 && (size_t)CB * PER_IMG > avail) CB >>= 1;

  zero_loss_k<<<dim3(1), 64, 0, stream>>>(out);
  repackA2_k<<<dim3(512), 256, 0, stream>>>(enc_w2, wCh, wCl);
  repackA_k<<<dim3(512), 256, 0, stream>>>(dec_w2, wAh, wAl);
  repackCB_k<<<dim3(128), 256, 0, stream>>>(cb, cbFh, cbFl);
  csqF_k<<<dim3(32), 256, 0, stream>>>(cb, csqF);

  for (int b0 = 0; b0 < 32; b0 += CB) {
    unsigned* hp = (unsigned*)dyn;                    // CB*2097152 (g aliases)
    float* zq = dyn + (size_t)CB * 2097152;           // CB*262144 (q_pk aliases)
    conv1_k<<<dim3(128, CB), 128, 0, stream>>>(
        x + (size_t)b0 * 65536, enc_w1, enc_b1, hp);
    conv2_k<<<dim3(32, CB), 512, 0, stream>>>(hp, wCh, wCl, enc_b2, zq);
    vq_k<<<dim3(CB * 64), 256, 0, stream>>>(
        zq, cb, cbFh, cbFl, csqF, (unsigned int*)zq, out, b0 * 4096);
    dconv2_k<<<dim3(64, CB), 512, 0, stream>>>(
        (const unsigned int*)zq, wAh, wAl, dec_b2, (float*)dyn /*g*/);
    dconv1_k<<<dim3(64, CB), 256, 0, stream>>>(
        (float*)dyn /*g*/, dec_w1, dec_b1, out + REC_OFF + (size_t)b0 * 65536);
  }
}

// Round 16
// 556.540 us; speedup vs baseline: 1.0207x; 1.0207x over previous
//
#include <hip/hip_runtime.h>
#include <math.h>

// ---------------------------------------------------------------------------
// VQ-VAE forward, bf16x3-MFMA for conv2, convT2 AND VQ distances.
//  x (32,1,256,256) -> h_pk (u32 hi|lo) -> z (f32) -> VQ -> q_pk (u32 hi|lo)
//  -> g (f32, aliases h_pk) -> x_recon (32,1,256,256)
// d_out: [0]=vq_loss, [1..131072]=idx (as float), [131073..]=x_recon
// Fragment conventions (HW-verified, absmax 0.0 rounds 4-15):
//   A/B: lane l holds k_local = 8*(l>>4)+j, m/n = l&15
//   C/D: row = (l>>4)*4 + reg, col = l&15
// Round 16: conv2 waves split over nt as well — 8 waves = Yloc(2) x mtg(2) x
// ntg(2), each wave owns 2mt x 2nt: B LDS reads & perms halve (B frag feeds
// 2 mt in-register); A read 2x (L1-resident 32KB/rnd). Output math identical.
// ---------------------------------------------------------------------------

#define REC_OFF 131073

typedef unsigned short ushort_t;
typedef __attribute__((ext_vector_type(8))) short bf16x8;
typedef __attribute__((ext_vector_type(4))) float f32x4;
typedef __attribute__((ext_vector_type(4))) unsigned int u32x4;
union FragU { u32x4 u; bf16x8 h; };

__device__ __forceinline__ unsigned pack_hilo(float v) {
  unsigned u = __float_as_uint(v);
  unsigned htop = u & 0xFFFF0000u;
  float rf = v - __uint_as_float(htop);
  return htop | (__float_as_uint(rf) >> 16);
}

__global__ __launch_bounds__(64) void zero_loss_k(float* __restrict__ out) {
  if (threadIdx.x == 0) out[0] = 0.f;
}

// ---- conv2 A-table: [ks=ci0*4+ky][mt][lane][j] bf16 hi/lo -----------------
__global__ __launch_bounds__(256) void repackA2_k(
    const float* __restrict__ ew2,
    ushort_t* __restrict__ hi, ushort_t* __restrict__ lo) {
  int idx = blockIdx.x * 256 + threadIdx.x;        // 131072 total
  int j = idx & 7, l = (idx >> 3) & 63, mt = (idx >> 9) & 3, ks = idx >> 11;
  int ci = ((ks >> 2) << 3) + ((l >> 4) << 1) + (j >> 2);
  int ky = ks & 3, kx = j & 3, d = (mt << 4) + (l & 15);
  float val = ew2[((d << 7) + ci) * 16 + (ky << 2) + kx];
  unsigned u = __float_as_uint(val);
  float rf = val - __uint_as_float(u & 0xFFFF0000u);
  hi[idx] = (ushort_t)(u >> 16);
  lo[idx] = (ushort_t)(__float_as_uint(rf) >> 16);
}

// ---- dconv2 A-table (proven) ----------------------------------------------
__global__ __launch_bounds__(256) void repackA_k(
    const float* __restrict__ dw2,   // dec_w2 (ci=64, co=128, ky, kx)
    ushort_t* __restrict__ hi, ushort_t* __restrict__ lo) {
  int idx = blockIdx.x * 256 + threadIdx.x;        // 131072 total
  int j = idx & 7, l = (idx >> 3) & 63, mt = (idx >> 9) & 7;
  int s = (idx >> 12) & 7, v = idx >> 15;
  int co = (mt << 4) + (l & 15);
  int ci = (s << 3) + ((l >> 4) << 1) + (j >> 2);
  int tap = j & 3;
  int Yp = v >> 1, pX = v & 1;
  int kyA = 1 - Yp, kyB = kyA + 2;
  int kxA = pX ? 0 : 1, kxB = kxA + 2;
  int ky = (tap & 2) ? kyB : kyA;
  int kx = (tap & 1) ? kxA : kxB;
  float val = dw2[(((ci << 7) + co) << 4) + (ky << 2) + kx];
  unsigned u = __float_as_uint(val);
  float rf = val - __uint_as_float(u & 0xFFFF0000u);
  hi[idx] = (ushort_t)(u >> 16);
  lo[idx] = (ushort_t)(__float_as_uint(rf) >> 16);
}

// ---- VQ codebook A-table: [ks(2)][mt(32)][lane(64)][j(8)] bf16 hi/lo ------
__global__ __launch_bounds__(256) void repackCB_k(
    const float* __restrict__ cb,
    ushort_t* __restrict__ hi, ushort_t* __restrict__ lo) {
  int idx = blockIdx.x * 256 + threadIdx.x;        // 32768 total
  int j = idx & 7, l = (idx >> 3) & 63, mt = (idx >> 9) & 31, ks = idx >> 14;
  int code = (mt << 4) + (l & 15);
  int k = (ks << 5) + ((l >> 4) << 3) + j;
  float val = cb[(code << 6) + k];
  unsigned u = __float_as_uint(val);
  float rf = val - __uint_as_float(u & 0xFFFF0000u);
  hi[idx] = (ushort_t)(u >> 16);
  lo[idx] = (ushort_t)(__float_as_uint(rf) >> 16);
}

// ---- csq in C/D fragment order: csqF[(mt*64+l)*4+r] = |cb[code]|^2 --------
__global__ __launch_bounds__(256) void csqF_k(
    const float* __restrict__ cb, float* __restrict__ csqF) {
  int idx = blockIdx.x * 256 + threadIdx.x;        // 8192 total
  int r = idx & 3, l = (idx >> 2) & 63, mt = idx >> 8;
  int code = (mt << 4) + ((l >> 4) << 2) + r;
  const float* cp = cb + (code << 6);
  float s = 0.f;
#pragma unroll
  for (int d = 0; d < 64; ++d) s = fmaf(cp[d], cp[d], s);
  csqF[idx] = s;
}

// ---------------- conv1 (1->128, 4x4, s2, p1) + relu -> packed u32 ----------
__global__ __launch_bounds__(128) void conv1_k(
    const float* __restrict__ x, const float* __restrict__ w1,
    const float* __restrict__ b1, unsigned* __restrict__ hp) {
  int oy = blockIdx.x, b = blockIdx.y, ox = threadIdx.x;
  float xv[16];
#pragma unroll
  for (int ky = 0; ky < 4; ++ky) {
    int iy = 2 * oy - 1 + ky;
#pragma unroll
    for (int kx = 0; kx < 4; ++kx) {
      int ix = 2 * ox - 1 + kx;
      float v = 0.f;
      if (iy >= 0 && iy < 256 && ix >= 0 && ix < 256)
        v = x[(b * 256 + iy) * 256 + ix];
      xv[ky * 4 + kx] = v;
    }
  }
  for (int c = 0; c < 128; ++c) {
    const float* wp = w1 + c * 16;                 // wave-uniform -> s_load
    float acc = b1[c];
#pragma unroll
    for (int k = 0; k < 16; ++k) acc = fmaf(xv[k], wp[k], acc);
    hp[((b * 128 + c) * 128 + oy) * 128 + ox] = pack_hilo(fmaxf(acc, 0.f));
  }
}

// ---------------- conv2 (128->64, 4x4, s2, p1) + relu: bf16x3 MFMA ----------
// 2 y-rows/block, 512 thr = 8 waves (Yloc=w>>2, mtg=(w>>1)&1, ntg=w&1).
// Wave owns mt in {2mtg,2mtg+1} x nt in {2ntg,2ntg+1}: B read once feeds
// both mt (LDS reads/perms halve vs round-15). 6 shared staged rows.
#define C2RL 133
__global__ __launch_bounds__(512) void conv2_k(
    const unsigned* __restrict__ hp, const ushort_t* __restrict__ wCh,
    const ushort_t* __restrict__ wCl, const float* __restrict__ b2,
    float* __restrict__ z) {
  __shared__ unsigned hs[8][6][C2RL];              // 25.5 KB
  int a = blockIdx.x, b = blockIdx.y;              // outputs y = 2a, 2a+1
  int t = threadIdx.x, l = t & 63;
  int w = __builtin_amdgcn_readfirstlane(t >> 6);  // 0..7
  int Yloc = w >> 2, mtg = (w >> 1) & 1, ntg = w & 1;
  int y = 2 * a + Yloc;
  int g = l >> 4;

  if (t < 48) {                                    // x-halo prezero
    int ci = t & 7, r = t >> 3;                    // r in 0..5
    hs[ci][r][0] = 0u;
    hs[ci][r][129] = 0u;
  }

  // staging coords: thread does 3 rows (r = r0, r0+2, r0+4)
  int c4 = t & 31, ci_l = (t >> 5) & 7, r0 = t >> 8;   // r0 in {0,1}
  int yr[3];
  bool rowok[3];
#pragma unroll
  for (int i = 0; i < 3; ++i) {
    yr[i] = 4 * a - 1 + r0 + 2 * i;
    rowok[i] = yr[i] >= 0 && yr[i] < 128;
  }
  const unsigned* hbase = hp + (((long)b * 128) << 14);

  u32x4 pre[3];
#pragma unroll
  for (int i = 0; i < 3; ++i)
    pre[i] = rowok[i]
        ? *reinterpret_cast<const u32x4*>(
              hbase + (((long)ci_l << 14) + (yr[i] << 7)) + (c4 << 2))
        : (u32x4)0u;

  f32x4 acc[2][2];
#pragma unroll
  for (int ml = 0; ml < 2; ++ml)
#pragma unroll
    for (int nl = 0; nl < 2; ++nl) acc[ml][nl] = (f32x4)0.f;

  for (int rnd = 0; rnd < 16; ++rnd) {
    __syncthreads();                               // buffer consumed / halo done
#pragma unroll
    for (int i = 0; i < 3; ++i) {
      unsigned* dst = &hs[ci_l][r0 + 2 * i][1 + (c4 << 2)];
      dst[0] = pre[i][0]; dst[1] = pre[i][1];
      dst[2] = pre[i][2]; dst[3] = pre[i][3];
    }
    __syncthreads();                               // tile visible
    if (rnd < 15) {
      long cb8 = ((long)((rnd + 1) * 8 + ci_l)) << 14;
#pragma unroll
      for (int i = 0; i < 3; ++i)
        pre[i] = rowok[i]
            ? *reinterpret_cast<const u32x4*>(
                  hbase + cb8 + (yr[i] << 7) + (c4 << 2))
            : (u32x4)0u;
    }
#pragma unroll
    for (int ky = 0; ky < 4; ++ky) {
      int ks = (rnd << 2) + ky;
      int row = 2 * Yloc + ky;                     // LDS row 0..5
      FragU ah[2], al_[2];
#pragma unroll
      for (int ml = 0; ml < 2; ++ml) {
        int mt = (mtg << 1) + ml;
        long aoff = (((long)ks * 4 + mt) * 64 + l) * 8;
        ah[ml].u = *reinterpret_cast<const u32x4*>(wCh + aoff);
        al_[ml].u = *reinterpret_cast<const u32x4*>(wCl + aoff);
      }
#pragma unroll
      for (int nl = 0; nl < 2; ++nl) {
        int nt = (ntg << 1) + nl;
        const unsigned* pa = &hs[g * 2][row][(nt << 5) + 2 * (l & 15)];
        const unsigned* pb = &hs[g * 2 + 1][row][(nt << 5) + 2 * (l & 15)];
        unsigned a0 = pa[0], a1 = pa[1], a2 = pa[2], a3 = pa[3];
        unsigned b0 = pb[0], b1 = pb[1], b2_ = pb[2], b3 = pb[3];
        FragU bh, bl;
        bh.u[0] = __builtin_amdgcn_perm(a1, a0, 0x07060302u);
        bl.u[0] = __builtin_amdgcn_perm(a1, a0, 0x05040100u);
        bh.u[1] = __builtin_amdgcn_perm(a3, a2, 0x07060302u);
        bl.u[1] = __builtin_amdgcn_perm(a3, a2, 0x05040100u);
        bh.u[2] = __builtin_amdgcn_perm(b1, b0, 0x07060302u);
        bl.u[2] = __builtin_amdgcn_perm(b1, b0, 0x05040100u);
        bh.u[3] = __builtin_amdgcn_perm(b3, b2_, 0x07060302u);
        bl.u[3] = __builtin_amdgcn_perm(b3, b2_, 0x05040100u);
#pragma unroll
        for (int ml = 0; ml < 2; ++ml) {
          acc[ml][nl] = __builtin_amdgcn_mfma_f32_16x16x32_bf16(
              ah[ml].h, bh.h, acc[ml][nl], 0, 0, 0);
          acc[ml][nl] = __builtin_amdgcn_mfma_f32_16x16x32_bf16(
              ah[ml].h, bl.h, acc[ml][nl], 0, 0, 0);
          acc[ml][nl] = __builtin_amdgcn_mfma_f32_16x16x32_bf16(
              al_[ml].h, bh.h, acc[ml][nl], 0, 0, 0);
        }
      }
    }
  }
#pragma unroll
  for (int ml = 0; ml < 2; ++ml) {
#pragma unroll
    for (int nl = 0; nl < 2; ++nl) {
#pragma unroll
      for (int r = 0; r < 4; ++r) {
        int d = (((mtg << 1) + ml) << 4) + (g << 2) + r;
        int x = (((ntg << 1) + nl) << 4) + (l & 15);
        float v = fmaxf(acc[ml][nl][r] + b2[d], 0.f);
        z[((b * 64 + d) * 64 + y) * 64 + x] = v;
      }
    }
  }
}

// ---------------- VQ: bf16x3 MFMA distances + fp32 argmin (chunked) ---------
__global__ __launch_bounds__(256) void vq_k(
    const float* z, const float* __restrict__ cb,
    const ushort_t* __restrict__ cbFh, const ushort_t* __restrict__ cbFl,
    const float* __restrict__ csqF, unsigned int* q_pk,
    float* __restrict__ out, int n0) {
  __shared__ unsigned zS[64 * 67];                 // 17.2 KB
  __shared__ int bk_arr[64];
  __shared__ float redl[4];
  int t = threadIdx.x, l = t & 63;
  int w = __builtin_amdgcn_readfirstlane(t >> 6);
  int nbase = blockIdx.x * 64;
  int b = nbase >> 12, y = (nbase >> 6) & 63;
  long zbase = (long)b * 262144 + y * 64;

  float zv[16];
#pragma unroll
  for (int j = 0; j < 16; ++j) {
    zv[j] = z[zbase + (long)((w << 4) + j) * 4096 + l];
    zS[l * 67 + (w << 4) + j] = pack_hilo(zv[j]);
  }
  __syncthreads();

  int pp = (w << 4) + (l & 15);
  FragU bh[2], bl[2];
#pragma unroll
  for (int ks = 0; ks < 2; ++ks) {
    const unsigned* zp = &zS[pp * 67 + (ks << 5) + ((l >> 4) << 3)];
    unsigned u0 = zp[0], u1 = zp[1], u2 = zp[2], u3 = zp[3];
    unsigned u4 = zp[4], u5 = zp[5], u6 = zp[6], u7 = zp[7];
    bh[ks].u[0] = __builtin_amdgcn_perm(u1, u0, 0x07060302u);
    bl[ks].u[0] = __builtin_amdgcn_perm(u1, u0, 0x05040100u);
    bh[ks].u[1] = __builtin_amdgcn_perm(u3, u2, 0x07060302u);
    bl[ks].u[1] = __builtin_amdgcn_perm(u3, u2, 0x05040100u);
    bh[ks].u[2] = __builtin_amdgcn_perm(u5, u4, 0x07060302u);
    bl[ks].u[2] = __builtin_amdgcn_perm(u5, u4, 0x05040100u);
    bh[ks].u[3] = __builtin_amdgcn_perm(u7, u6, 0x07060302u);
    bl[ks].u[3] = __builtin_amdgcn_perm(u7, u6, 0x05040100u);
  }

  int g = l >> 4;
  float bd = 1e30f;
  int bk = 0;
  for (int mc = 0; mc < 4; ++mc) {                 // 128 codes per chunk
    f32x4 acc[8];
#pragma unroll
    for (int m8 = 0; m8 < 8; ++m8) acc[m8] = (f32x4)0.f;
#pragma unroll
    for (int ks = 0; ks < 2; ++ks) {
#pragma unroll
      for (int m8 = 0; m8 < 8; ++m8) {
        long aoff = (((long)(ks * 32 + mc * 8 + m8) * 64) + l) * 8;
        FragU ah, al_;
        ah.u = *reinterpret_cast<const u32x4*>(cbFh + aoff);
        al_.u = *reinterpret_cast<const u32x4*>(cbFl + aoff);
        acc[m8] = __builtin_amdgcn_mfma_f32_16x16x32_bf16(
            ah.h, bh[ks].h, acc[m8], 0, 0, 0);
        acc[m8] = __builtin_amdgcn_mfma_f32_16x16x32_bf16(
            ah.h, bl[ks].h, acc[m8], 0, 0, 0);
        acc[m8] = __builtin_amdgcn_mfma_f32_16x16x32_bf16(
            al_.h, bh[ks].h, acc[m8], 0, 0, 0);
      }
    }
#pragma unroll
    for (int m8 = 0; m8 < 8; ++m8) {
      int mt = mc * 8 + m8;
      f32x4 cq = *reinterpret_cast<const f32x4*>(csqF + ((mt << 6) + l) * 4);
#pragma unroll
      for (int r = 0; r < 4; ++r) {
        float d = fmaf(-2.f, acc[m8][r], cq[r]);
        if (d < bd) { bd = d; bk = (mt << 4) + (g << 2) + r; }
      }
    }
  }
#pragma unroll
  for (int m = 16; m <= 32; m <<= 1) {
    float d2 = __shfl_xor(bd, m);
    int k2 = __shfl_xor(bk, m);
    if (d2 < bd || (d2 == bd && k2 < bk)) { bd = d2; bk = k2; }
  }
  if (l < 16) {
    bk_arr[(w << 4) + l] = bk;
    out[1 + n0 + nbase + (w << 4) + l] = (float)bk;
  }
  __syncthreads();

  int bkp = bk_arr[l];
  const float* cbest = cb + (bkp << 6) + (w << 4);
  float ls = 0.f;
#pragma unroll
  for (int j = 0; j < 16; ++j) {
    float c = cbest[j];
    q_pk[zbase + (long)((w << 4) + j) * 4096 + l] = pack_hilo(c);
    float df = c - zv[j];
    ls = fmaf(df, df, ls);
  }
#pragma unroll
  for (int m = 32; m; m >>= 1) ls += __shfl_xor(ls, m);
  if (l == 0) redl[w] = ls;
  __syncthreads();
  if (t == 0)
    atomicAdd(out, (redl[0] + redl[1] + redl[2] + redl[3]) * (1.25f / 8388608.f));
}

// ---------------- convT2 (64->128, 4x4, s2, p1) + relu: bf16x3 MFMA ---------
// 2 Y-rows per block, 512 thr = 8 waves (proven round 14).
__global__ __launch_bounds__(512) void dconv2_k(
    const unsigned int* __restrict__ q_pk, const ushort_t* __restrict__ wAh,
    const ushort_t* __restrict__ wAl, const float* __restrict__ db2,
    float* __restrict__ g) {
  __shared__ unsigned int rows[64][3][68];         // 52,224 B
  int a = blockIdx.x, b = blockIdx.y;              // Y0 = 2a
  int t = threadIdx.x, l = t & 63;
  int w = __builtin_amdgcn_readfirstlane(t >> 6);  // 0..7
  int Yloc = w >> 2, pX = w & 1, coh = (w >> 1) & 1;
  int Y = 2 * a + Yloc;
  int v = (Yloc << 1) | pX;                        // = ((Y&1)<<1)|pX
  int rA = Yloc + 1, rB = Yloc;                    // LDS row idx: yA, yB

  if (t < 192) {
    int ci = t & 63, r = t >> 6;
    rows[ci][r][0] = 0u;
    rows[ci][r][65] = 0u;
  }
  long qb = (long)b * 262144;
#pragma unroll
  for (int r = 0; r < 3; ++r) {
    int yr = a - 1 + r;
    bool ok = (yr >= 0) && (yr < 64);
    for (int s = t; s < 1024; s += 512) {          // 2 iters
      int ci = s >> 4, c4 = s & 15;
      u32x4 val = ok ? *reinterpret_cast<const u32x4*>(
                           q_pk + qb + ci * 4096 + yr * 64 + (c4 << 2))
                     : (u32x4)0u;
      unsigned* dst = &rows[ci][r][1 + (c4 << 2)];
      dst[0] = val[0]; dst[1] = val[1]; dst[2] = val[2]; dst[3] = val[3];
    }
  }
  __syncthreads();

  f32x4 acc[4][4];
#pragma unroll
  for (int mt = 0; mt < 4; ++mt)
#pragma unroll
    for (int nt = 0; nt < 4; ++nt) acc[mt][nt] = (f32x4)0.f;

  for (int s8 = 0; s8 < 8; ++s8) {
    FragU ah[4], al[4];
#pragma unroll
    for (int mt = 0; mt < 4; ++mt) {
      long off = ((((long)(v * 8 + s8) * 8 + (coh * 4 + mt)) * 64 + l) * 8);
      ah[mt].u = *reinterpret_cast<const u32x4*>(wAh + off);
      al[mt].u = *reinterpret_cast<const u32x4*>(wAl + off);
    }
#pragma unroll
    for (int nt = 0; nt < 4; ++nt) {
      int p = nt * 16 + (l & 15) + pX;
      int cc0 = (s8 << 3) + ((l >> 4) << 1);
      unsigned u0 = rows[cc0][rA][p], u1 = rows[cc0][rA][p + 1];
      unsigned u2 = rows[cc0][rB][p], u3 = rows[cc0][rB][p + 1];
      unsigned u4 = rows[cc0 + 1][rA][p], u5 = rows[cc0 + 1][rA][p + 1];
      unsigned u6 = rows[cc0 + 1][rB][p], u7 = rows[cc0 + 1][rB][p + 1];
      FragU bh, bl;
      bh.u[0] = (u0 >> 16) | (u1 & 0xFFFF0000u);
      bl.u[0] = (u0 & 0xFFFFu) | (u1 << 16);
      bh.u[1] = (u2 >> 16) | (u3 & 0xFFFF0000u);
      bl.u[1] = (u2 & 0xFFFFu) | (u3 << 16);
      bh.u[2] = (u4 >> 16) | (u5 & 0xFFFF0000u);
      bl.u[2] = (u4 & 0xFFFFu) | (u5 << 16);
      bh.u[3] = (u6 >> 16) | (u7 & 0xFFFF0000u);
      bl.u[3] = (u6 & 0xFFFFu) | (u7 << 16);
#pragma unroll
      for (int mt = 0; mt < 4; ++mt) {
        acc[mt][nt] = __builtin_amdgcn_mfma_f32_16x16x32_bf16(
            ah[mt].h, bh.h, acc[mt][nt], 0, 0, 0);
        acc[mt][nt] = __builtin_amdgcn_mfma_f32_16x16x32_bf16(
            ah[mt].h, bl.h, acc[mt][nt], 0, 0, 0);
        acc[mt][nt] = __builtin_amdgcn_mfma_f32_16x16x32_bf16(
            al[mt].h, bh.h, acc[mt][nt], 0, 0, 0);
      }
    }
  }

#pragma unroll
  for (int mt = 0; mt < 4; ++mt) {
#pragma unroll
    for (int r = 0; r < 4; ++r) {
      int co = ((coh * 4 + mt) << 4) + ((l >> 4) << 2) + r;
      float bias = db2[co];
#pragma unroll
      for (int nt = 0; nt < 4; ++nt) {
        int X = ((nt << 4) + (l & 15)) * 2 + pX;
        float val = fmaxf(acc[mt][nt][r] + bias, 0.f);
        g[((b * 128 + co) * 128 + Y) * 128 + X] = val;
      }
    }
  }
}

// ---------------- convT1 (128->1, 4x4, s2, p1) + sigmoid --------------------
__global__ __launch_bounds__(256) void dconv1_k(
    const float* __restrict__ g, const float* __restrict__ wd1,
    const float* __restrict__ db1, float* __restrict__ rec) {
  int a2 = blockIdx.x, b = blockIdx.y;
  int t = threadIdx.x;
  int w = __builtin_amdgcn_readfirstlane(t >> 6);
  int l = t & 63;
  int xh = w >> 1, pX = w & 1;
  int L = xh * 64 + l;                       // X = 2L + pX
  int kxA = pX ? 0 : 1, kxB = kxA + 2;
  int ixH = L + pX, ixL = L + pX - 1;
  bool okH = ixH < 128, okL = ixL >= 0;
  int yy0 = 2 * a2 - 1;
  bool vy[4];
#pragma unroll
  for (int r = 0; r < 4; ++r) vy[r] = (yy0 + r) >= 0 && (yy0 + r) < 128;

  const float* gb = g + ((long)b * 128) * 16384 + (long)yy0 * 128;
  float acc[4] = {0.f, 0.f, 0.f, 0.f};

  for (int ci = 0; ci < 128; ci += 2) {
    const float* p0 = gb + (long)ci * 16384;
    const float* p1 = p0 + 16384;
    float hi0[4], lo0[4], hi1[4], lo1[4];
#pragma unroll
    for (int r = 0; r < 4; ++r) {
      const float* q0 = p0 + r * 128;
      const float* q1 = p1 + r * 128;
      hi0[r] = (vy[r] && okH) ? q0[ixH] : 0.f;
      lo0[r] = (vy[r] && okL) ? q0[ixL] : 0.f;
      hi1[r] = (vy[r] && okH) ? q1[ixH] : 0.f;
      lo1[r] = (vy[r] && okL) ? q1[ixL] : 0.f;
    }
    const float* wp0 = wd1 + ci * 16;        // wave-uniform -> s_load
    const float* wp1 = wp0 + 16;
#pragma unroll
    for (int j = 0; j < 4; ++j) {
      int kyA = (j + 1) & 1, kyB = kyA + 2;
      int rA = ((j + 1) >> 1) + 1;           // in [1,3]
      float v = acc[j];
      v = fmaf(wp0[kyA * 4 + kxA], hi0[rA], v);
      v = fmaf(wp0[kyA * 4 + kxB], lo0[rA], v);
      v = fmaf(wp0[kyB * 4 + kxA], hi0[rA - 1], v);
      v = fmaf(wp0[kyB * 4 + kxB], lo0[rA - 1], v);
      v = fmaf(wp1[kyA * 4 + kxA], hi1[rA], v);
      v = fmaf(wp1[kyA * 4 + kxB], lo1[rA], v);
      v = fmaf(wp1[kyB * 4 + kxA], hi1[rA - 1], v);
      v = fmaf(wp1[kyB * 4 + kxB], lo1[rA - 1], v);
      acc[j] = v;
    }
  }
  float bb = db1[0];
#pragma unroll
  for (int j = 0; j < 4; ++j) {
    float v = acc[j] + bb;
    v = 1.f / (1.f + __expf(-v));
    rec[((b * 256 + 4 * a2 + j) * 256) + 2 * L + pX] = v;
  }
}

// ---------------------------------------------------------------------------
extern "C" void kernel_launch(void* const* d_in, const int* in_sizes, int n_in,
                              void* d_out, int out_size, void* d_ws, size_t ws_size,
                              hipStream_t stream) {
  const float* x      = (const float*)d_in[0];
  const float* enc_w1 = (const float*)d_in[1];
  const float* enc_b1 = (const float*)d_in[2];
  const float* enc_w2 = (const float*)d_in[3];
  const float* enc_b2 = (const float*)d_in[4];
  const float* cb     = (const float*)d_in[5];
  const float* dec_w2 = (const float*)d_in[6];
  const float* dec_b2 = (const float*)d_in[7];
  const float* dec_w1 = (const float*)d_in[8];
  const float* dec_b1 = (const float*)d_in[9];

  float* out = (float*)d_out;
  float* ws  = (float*)d_ws;
  ushort_t* wCh  = (ushort_t*)ws;                   // 131072 ushort = 65536 f
  ushort_t* wCl  = (ushort_t*)(ws + 65536);
  ushort_t* wAh  = (ushort_t*)(ws + 131072);
  ushort_t* wAl  = (ushort_t*)(ws + 196608);
  ushort_t* cbFh = (ushort_t*)(ws + 262144);        // 32768 ushort = 16384 f
  ushort_t* cbFl = (ushort_t*)(ws + 278528);
  float* csqF = ws + 294912;                        // 8192 f
  float* dyn  = ws + 303104;                        // chunk buffers

  // Per-image: h_pk = 2,097,152 u32 (g f32 aliases), z/q_pk = 262,144.
  const size_t PER_IMG = 2097152 + 262144;                   // 2,359,296 elems
  size_t avail = (ws_size / 4 > 303104 + 64) ? ws_size / 4 - 303104 - 64 : 0;
  int CB = 32;
  while (CB > 1 && (size_t)CB * PER_IMG > avail) CB >>= 1;

  zero_loss_k<<<dim3(1), 64, 0, stream>>>(out);
  repackA2_k<<<dim3(512), 256, 0, stream>>>(enc_w2, wCh, wCl);
  repackA_k<<<dim3(512), 256, 0, stream>>>(dec_w2, wAh, wAl);
  repackCB_k<<<dim3(128), 256, 0, stream>>>(cb, cbFh, cbFl);
  csqF_k<<<dim3(32), 256, 0, stream>>>(cb, csqF);

  for (int b0 = 0; b0 < 32; b0 += CB) {
    unsigned* hp = (unsigned*)dyn;                    // CB*2097152 (g aliases)
    float* zq = dyn + (size_t)CB * 2097152;           // CB*262144 (q_pk aliases)
    conv1_k<<<dim3(128, CB), 128, 0, stream>>>(
        x + (size_t)b0 * 65536, enc_w1, enc_b1, hp);
    conv2_k<<<dim3(32, CB), 512, 0, stream>>>(hp, wCh, wCl, enc_b2, zq);
    vq_k<<<dim3(CB * 64), 256, 0, stream>>>(
        zq, cb, cbFh, cbFl, csqF, (unsigned int*)zq, out, b0 * 4096);
    dconv2_k<<<dim3(64, CB), 512, 0, stream>>>(
        (const unsigned int*)zq, wAh, wAl, dec_b2, (float*)dyn /*g*/);
    dconv1_k<<<dim3(64, CB), 256, 0, stream>>>(
        (float*)dyn /*g*/, dec_w1, dec_b1, out + REC_OFF + (size_t)b0 * 65536);
  }
}

// Round 17
// 543.410 us; speedup vs baseline: 1.0454x; 1.0242x over previous
//
#include <hip/hip_runtime.h>
#include <math.h>

// ---------------------------------------------------------------------------
// VQ-VAE forward, bf16x3-MFMA for conv2, convT2 AND VQ distances.
//  x (32,1,256,256) -> h_pk (u32 hi|lo) -> z (f32) -> VQ -> q_pk (u32 hi|lo)
//  -> g (f32, aliases h_pk) -> x_recon (32,1,256,256)
// d_out: [0]=vq_loss, [1..131072]=idx (as float), [131073..]=x_recon
// Fragment conventions (HW-verified, absmax 0.0 rounds 4-16):
//   A/B: lane l holds k_local = 8*(l>>4)+j, m/n = l&15
//   C/D: row = (l>>4)*4 + reg, col = l&15
// Round 17: conv2 LDS double-buffer (hs[2][...], 51KB) — one barrier/round
// instead of two; tile n+1 ds_writes overlap tile n MFMAs. At 1 block/CU the
// barrier is a full-CU stall, so halving barrier count is the residual lever.
// ---------------------------------------------------------------------------

#define REC_OFF 131073

typedef unsigned short ushort_t;
typedef __attribute__((ext_vector_type(8))) short bf16x8;
typedef __attribute__((ext_vector_type(4))) float f32x4;
typedef __attribute__((ext_vector_type(4))) unsigned int u32x4;
union FragU { u32x4 u; bf16x8 h; };

__device__ __forceinline__ unsigned pack_hilo(float v) {
  unsigned u = __float_as_uint(v);
  unsigned htop = u & 0xFFFF0000u;
  float rf = v - __uint_as_float(htop);
  return htop | (__float_as_uint(rf) >> 16);
}

__global__ __launch_bounds__(64) void zero_loss_k(float* __restrict__ out) {
  if (threadIdx.x == 0) out[0] = 0.f;
}

// ---- conv2 A-table: [ks=ci0*4+ky][mt][lane][j] bf16 hi/lo -----------------
__global__ __launch_bounds__(256) void repackA2_k(
    const float* __restrict__ ew2,
    ushort_t* __restrict__ hi, ushort_t* __restrict__ lo) {
  int idx = blockIdx.x * 256 + threadIdx.x;        // 131072 total
  int j = idx & 7, l = (idx >> 3) & 63, mt = (idx >> 9) & 3, ks = idx >> 11;
  int ci = ((ks >> 2) << 3) + ((l >> 4) << 1) + (j >> 2);
  int ky = ks & 3, kx = j & 3, d = (mt << 4) + (l & 15);
  float val = ew2[((d << 7) + ci) * 16 + (ky << 2) + kx];
  unsigned u = __float_as_uint(val);
  float rf = val - __uint_as_float(u & 0xFFFF0000u);
  hi[idx] = (ushort_t)(u >> 16);
  lo[idx] = (ushort_t)(__float_as_uint(rf) >> 16);
}

// ---- dconv2 A-table (proven) ----------------------------------------------
__global__ __launch_bounds__(256) void repackA_k(
    const float* __restrict__ dw2,   // dec_w2 (ci=64, co=128, ky, kx)
    ushort_t* __restrict__ hi, ushort_t* __restrict__ lo) {
  int idx = blockIdx.x * 256 + threadIdx.x;        // 131072 total
  int j = idx & 7, l = (idx >> 3) & 63, mt = (idx >> 9) & 7;
  int s = (idx >> 12) & 7, v = idx >> 15;
  int co = (mt << 4) + (l & 15);
  int ci = (s << 3) + ((l >> 4) << 1) + (j >> 2);
  int tap = j & 3;
  int Yp = v >> 1, pX = v & 1;
  int kyA = 1 - Yp, kyB = kyA + 2;
  int kxA = pX ? 0 : 1, kxB = kxA + 2;
  int ky = (tap & 2) ? kyB : kyA;
  int kx = (tap & 1) ? kxA : kxB;
  float val = dw2[(((ci << 7) + co) << 4) + (ky << 2) + kx];
  unsigned u = __float_as_uint(val);
  float rf = val - __uint_as_float(u & 0xFFFF0000u);
  hi[idx] = (ushort_t)(u >> 16);
  lo[idx] = (ushort_t)(__float_as_uint(rf) >> 16);
}

// ---- VQ codebook A-table: [ks(2)][mt(32)][lane(64)][j(8)] bf16 hi/lo ------
__global__ __launch_bounds__(256) void repackCB_k(
    const float* __restrict__ cb,
    ushort_t* __restrict__ hi, ushort_t* __restrict__ lo) {
  int idx = blockIdx.x * 256 + threadIdx.x;        // 32768 total
  int j = idx & 7, l = (idx >> 3) & 63, mt = (idx >> 9) & 31, ks = idx >> 14;
  int code = (mt << 4) + (l & 15);
  int k = (ks << 5) + ((l >> 4) << 3) + j;
  float val = cb[(code << 6) + k];
  unsigned u = __float_as_uint(val);
  float rf = val - __uint_as_float(u & 0xFFFF0000u);
  hi[idx] = (ushort_t)(u >> 16);
  lo[idx] = (ushort_t)(__float_as_uint(rf) >> 16);
}

// ---- csq in C/D fragment order: csqF[(mt*64+l)*4+r] = |cb[code]|^2 --------
__global__ __launch_bounds__(256) void csqF_k(
    const float* __restrict__ cb, float* __restrict__ csqF) {
  int idx = blockIdx.x * 256 + threadIdx.x;        // 8192 total
  int r = idx & 3, l = (idx >> 2) & 63, mt = idx >> 8;
  int code = (mt << 4) + ((l >> 4) << 2) + r;
  const float* cp = cb + (code << 6);
  float s = 0.f;
#pragma unroll
  for (int d = 0; d < 64; ++d) s = fmaf(cp[d], cp[d], s);
  csqF[idx] = s;
}

// ---------------- conv1 (1->128, 4x4, s2, p1) + relu -> packed u32 ----------
__global__ __launch_bounds__(128) void conv1_k(
    const float* __restrict__ x, const float* __restrict__ w1,
    const float* __restrict__ b1, unsigned* __restrict__ hp) {
  int oy = blockIdx.x, b = blockIdx.y, ox = threadIdx.x;
  float xv[16];
#pragma unroll
  for (int ky = 0; ky < 4; ++ky) {
    int iy = 2 * oy - 1 + ky;
#pragma unroll
    for (int kx = 0; kx < 4; ++kx) {
      int ix = 2 * ox - 1 + kx;
      float v = 0.f;
      if (iy >= 0 && iy < 256 && ix >= 0 && ix < 256)
        v = x[(b * 256 + iy) * 256 + ix];
      xv[ky * 4 + kx] = v;
    }
  }
  for (int c = 0; c < 128; ++c) {
    const float* wp = w1 + c * 16;                 // wave-uniform -> s_load
    float acc = b1[c];
#pragma unroll
    for (int k = 0; k < 16; ++k) acc = fmaf(xv[k], wp[k], acc);
    hp[((b * 128 + c) * 128 + oy) * 128 + ox] = pack_hilo(fmaxf(acc, 0.f));
  }
}

// ---------------- conv2 (128->64, 4x4, s2, p1) + relu: bf16x3 MFMA ----------
// 2 y-rows/block, 512 thr = 8 waves (Yloc=w>>2, mtg=(w>>1)&1, ntg=w&1),
// wave owns 2mt x 2nt (round 16). LDS double-buffered: 1 barrier/round,
// tile n+1 writes overlap tile n MFMAs. 6 shared staged rows per buffer.
#define C2RL 133
__global__ __launch_bounds__(512) void conv2_k(
    const unsigned* __restrict__ hp, const ushort_t* __restrict__ wCh,
    const ushort_t* __restrict__ wCl, const float* __restrict__ b2,
    float* __restrict__ z) {
  __shared__ unsigned hs[2][8][6][C2RL];           // 51,072 B
  int a = blockIdx.x, b = blockIdx.y;              // outputs y = 2a, 2a+1
  int t = threadIdx.x, l = t & 63;
  int w = __builtin_amdgcn_readfirstlane(t >> 6);  // 0..7
  int Yloc = w >> 2, mtg = (w >> 1) & 1, ntg = w & 1;
  int y = 2 * a + Yloc;
  int g = l >> 4;

  if (t < 48) {                                    // x-halo prezero, both bufs
    int ci = t & 7, r = t >> 3;                    // r in 0..5
    hs[0][ci][r][0] = 0u;
    hs[0][ci][r][129] = 0u;
    hs[1][ci][r][0] = 0u;
    hs[1][ci][r][129] = 0u;
  }

  // staging coords: thread does 3 rows (r = r0, r0+2, r0+4)
  int c4 = t & 31, ci_l = (t >> 5) & 7, r0 = t >> 8;   // r0 in {0,1}
  int yr[3];
  bool rowok[3];
#pragma unroll
  for (int i = 0; i < 3; ++i) {
    yr[i] = 4 * a - 1 + r0 + 2 * i;
    rowok[i] = yr[i] >= 0 && yr[i] < 128;
  }
  const unsigned* hbase = hp + (((long)b * 128) << 14);

  u32x4 pre[3];
#pragma unroll
  for (int i = 0; i < 3; ++i)
    pre[i] = rowok[i]
        ? *reinterpret_cast<const u32x4*>(
              hbase + (((long)ci_l << 14) + (yr[i] << 7)) + (c4 << 2))
        : (u32x4)0u;
#pragma unroll
  for (int i = 0; i < 3; ++i) {                    // write tile 0 -> buf 0
    unsigned* dst = &hs[0][ci_l][r0 + 2 * i][1 + (c4 << 2)];
    dst[0] = pre[i][0]; dst[1] = pre[i][1];
    dst[2] = pre[i][2]; dst[3] = pre[i][3];
  }
  __syncthreads();

  f32x4 acc[2][2];
#pragma unroll
  for (int ml = 0; ml < 2; ++ml)
#pragma unroll
    for (int nl = 0; nl < 2; ++nl) acc[ml][nl] = (f32x4)0.f;

  for (int rnd = 0; rnd < 16; ++rnd) {
    int cur = rnd & 1;
    if (rnd < 15) {                                // issue next-tile loads
      long cb8 = ((long)((rnd + 1) * 8 + ci_l)) << 14;
#pragma unroll
      for (int i = 0; i < 3; ++i)
        pre[i] = rowok[i]
            ? *reinterpret_cast<const u32x4*>(
                  hbase + cb8 + (yr[i] << 7) + (c4 << 2))
            : (u32x4)0u;
    }
#pragma unroll
    for (int ky = 0; ky < 4; ++ky) {
      int ks = (rnd << 2) + ky;
      int row = 2 * Yloc + ky;                     // LDS row 0..5
      FragU ah[2], al_[2];
#pragma unroll
      for (int ml = 0; ml < 2; ++ml) {
        int mt = (mtg << 1) + ml;
        long aoff = (((long)ks * 4 + mt) * 64 + l) * 8;
        ah[ml].u = *reinterpret_cast<const u32x4*>(wCh + aoff);
        al_[ml].u = *reinterpret_cast<const u32x4*>(wCl + aoff);
      }
#pragma unroll
      for (int nl = 0; nl < 2; ++nl) {
        int nt = (ntg << 1) + nl;
        const unsigned* pa = &hs[cur][g * 2][row][(nt << 5) + 2 * (l & 15)];
        const unsigned* pb = &hs[cur][g * 2 + 1][row][(nt << 5) + 2 * (l & 15)];
        unsigned a0 = pa[0], a1 = pa[1], a2 = pa[2], a3 = pa[3];
        unsigned b0 = pb[0], b1 = pb[1], b2_ = pb[2], b3 = pb[3];
        FragU bh, bl;
        bh.u[0] = __builtin_amdgcn_perm(a1, a0, 0x07060302u);
        bl.u[0] = __builtin_amdgcn_perm(a1, a0, 0x05040100u);
        bh.u[1] = __builtin_amdgcn_perm(a3, a2, 0x07060302u);
        bl.u[1] = __builtin_amdgcn_perm(a3, a2, 0x05040100u);
        bh.u[2] = __builtin_amdgcn_perm(b1, b0, 0x07060302u);
        bl.u[2] = __builtin_amdgcn_perm(b1, b0, 0x05040100u);
        bh.u[3] = __builtin_amdgcn_perm(b3, b2_, 0x07060302u);
        bl.u[3] = __builtin_amdgcn_perm(b3, b2_, 0x05040100u);
#pragma unroll
        for (int ml = 0; ml < 2; ++ml) {
          acc[ml][nl] = __builtin_amdgcn_mfma_f32_16x16x32_bf16(
              ah[ml].h, bh.h, acc[ml][nl], 0, 0, 0);
          acc[ml][nl] = __builtin_amdgcn_mfma_f32_16x16x32_bf16(
              ah[ml].h, bl.h, acc[ml][nl], 0, 0, 0);
          acc[ml][nl] = __builtin_amdgcn_mfma_f32_16x16x32_bf16(
              al_[ml].h, bh.h, acc[ml][nl], 0, 0, 0);
        }
      }
    }
    if (rnd < 15) {                                // write next tile -> buf^1
#pragma unroll
      for (int i = 0; i < 3; ++i) {
        unsigned* dst = &hs[cur ^ 1][ci_l][r0 + 2 * i][1 + (c4 << 2)];
        dst[0] = pre[i][0]; dst[1] = pre[i][1];
        dst[2] = pre[i][2]; dst[3] = pre[i][3];
      }
      __syncthreads();                             // next buf visible; cur free
    }
  }
#pragma unroll
  for (int ml = 0; ml < 2; ++ml) {
#pragma unroll
    for (int nl = 0; nl < 2; ++nl) {
#pragma unroll
      for (int r = 0; r < 4; ++r) {
        int d = (((mtg << 1) + ml) << 4) + (g << 2) + r;
        int x = (((ntg << 1) + nl) << 4) + (l & 15);
        float v = fmaxf(acc[ml][nl][r] + b2[d], 0.f);
        z[((b * 64 + d) * 64 + y) * 64 + x] = v;
      }
    }
  }
}

// ---------------- VQ: bf16x3 MFMA distances + fp32 argmin (chunked) ---------
__global__ __launch_bounds__(256) void vq_k(
    const float* z, const float* __restrict__ cb,
    const ushort_t* __restrict__ cbFh, const ushort_t* __restrict__ cbFl,
    const float* __restrict__ csqF, unsigned int* q_pk,
    float* __restrict__ out, int n0) {
  __shared__ unsigned zS[64 * 67];                 // 17.2 KB
  __shared__ int bk_arr[64];
  __shared__ float redl[4];
  int t = threadIdx.x, l = t & 63;
  int w = __builtin_amdgcn_readfirstlane(t >> 6);
  int nbase = blockIdx.x * 64;
  int b = nbase >> 12, y = (nbase >> 6) & 63;
  long zbase = (long)b * 262144 + y * 64;

  float zv[16];
#pragma unroll
  for (int j = 0; j < 16; ++j) {
    zv[j] = z[zbase + (long)((w << 4) + j) * 4096 + l];
    zS[l * 67 + (w << 4) + j] = pack_hilo(zv[j]);
  }
  __syncthreads();

  int pp = (w << 4) + (l & 15);
  FragU bh[2], bl[2];
#pragma unroll
  for (int ks = 0; ks < 2; ++ks) {
    const unsigned* zp = &zS[pp * 67 + (ks << 5) + ((l >> 4) << 3)];
    unsigned u0 = zp[0], u1 = zp[1], u2 = zp[2], u3 = zp[3];
    unsigned u4 = zp[4], u5 = zp[5], u6 = zp[6], u7 = zp[7];
    bh[ks].u[0] = __builtin_amdgcn_perm(u1, u0, 0x07060302u);
    bl[ks].u[0] = __builtin_amdgcn_perm(u1, u0, 0x05040100u);
    bh[ks].u[1] = __builtin_amdgcn_perm(u3, u2, 0x07060302u);
    bl[ks].u[1] = __builtin_amdgcn_perm(u3, u2, 0x05040100u);
    bh[ks].u[2] = __builtin_amdgcn_perm(u5, u4, 0x07060302u);
    bl[ks].u[2] = __builtin_amdgcn_perm(u5, u4, 0x05040100u);
    bh[ks].u[3] = __builtin_amdgcn_perm(u7, u6, 0x07060302u);
    bl[ks].u[3] = __builtin_amdgcn_perm(u7, u6, 0x05040100u);
  }

  int g = l >> 4;
  float bd = 1e30f;
  int bk = 0;
  for (int mc = 0; mc < 4; ++mc) {                 // 128 codes per chunk
    f32x4 acc[8];
#pragma unroll
    for (int m8 = 0; m8 < 8; ++m8) acc[m8] = (f32x4)0.f;
#pragma unroll
    for (int ks = 0; ks < 2; ++ks) {
#pragma unroll
      for (int m8 = 0; m8 < 8; ++m8) {
        long aoff = (((long)(ks * 32 + mc * 8 + m8) * 64) + l) * 8;
        FragU ah, al_;
        ah.u = *reinterpret_cast<const u32x4*>(cbFh + aoff);
        al_.u = *reinterpret_cast<const u32x4*>(cbFl + aoff);
        acc[m8] = __builtin_amdgcn_mfma_f32_16x16x32_bf16(
            ah.h, bh[ks].h, acc[m8], 0, 0, 0);
        acc[m8] = __builtin_amdgcn_mfma_f32_16x16x32_bf16(
            ah.h, bl[ks].h, acc[m8], 0, 0, 0);
        acc[m8] = __builtin_amdgcn_mfma_f32_16x16x32_bf16(
            al_.h, bh[ks].h, acc[m8], 0, 0, 0);
      }
    }
#pragma unroll
    for (int m8 = 0; m8 < 8; ++m8) {
      int mt = mc * 8 + m8;
      f32x4 cq = *reinterpret_cast<const f32x4*>(csqF + ((mt << 6) + l) * 4);
#pragma unroll
      for (int r = 0; r < 4; ++r) {
        float d = fmaf(-2.f, acc[m8][r], cq[r]);
        if (d < bd) { bd = d; bk = (mt << 4) + (g << 2) + r; }
      }
    }
  }
#pragma unroll
  for (int m = 16; m <= 32; m <<= 1) {
    float d2 = __shfl_xor(bd, m);
    int k2 = __shfl_xor(bk, m);
    if (d2 < bd || (d2 == bd && k2 < bk)) { bd = d2; bk = k2; }
  }
  if (l < 16) {
    bk_arr[(w << 4) + l] = bk;
    out[1 + n0 + nbase + (w << 4) + l] = (float)bk;
  }
  __syncthreads();

  int bkp = bk_arr[l];
  const float* cbest = cb + (bkp << 6) + (w << 4);
  float ls = 0.f;
#pragma unroll
  for (int j = 0; j < 16; ++j) {
    float c = cbest[j];
    q_pk[zbase + (long)((w << 4) + j) * 4096 + l] = pack_hilo(c);
    float df = c - zv[j];
    ls = fmaf(df, df, ls);
  }
#pragma unroll
  for (int m = 32; m; m >>= 1) ls += __shfl_xor(ls, m);
  if (l == 0) redl[w] = ls;
  __syncthreads();
  if (t == 0)
    atomicAdd(out, (redl[0] + redl[1] + redl[2] + redl[3]) * (1.25f / 8388608.f));
}

// ---------------- convT2 (64->128, 4x4, s2, p1) + relu: bf16x3 MFMA ---------
// 2 Y-rows per block, 512 thr = 8 waves (proven round 14).
__global__ __launch_bounds__(512) void dconv2_k(
    const unsigned int* __restrict__ q_pk, const ushort_t* __restrict__ wAh,
    const ushort_t* __restrict__ wAl, const float* __restrict__ db2,
    float* __restrict__ g) {
  __shared__ unsigned int rows[64][3][68];         // 52,224 B
  int a = blockIdx.x, b = blockIdx.y;              // Y0 = 2a
  int t = threadIdx.x, l = t & 63;
  int w = __builtin_amdgcn_readfirstlane(t >> 6);  // 0..7
  int Yloc = w >> 2, pX = w & 1, coh = (w >> 1) & 1;
  int Y = 2 * a + Yloc;
  int v = (Yloc << 1) | pX;                        // = ((Y&1)<<1)|pX
  int rA = Yloc + 1, rB = Yloc;                    // LDS row idx: yA, yB

  if (t < 192) {
    int ci = t & 63, r = t >> 6;
    rows[ci][r][0] = 0u;
    rows[ci][r][65] = 0u;
  }
  long qb = (long)b * 262144;
#pragma unroll
  for (int r = 0; r < 3; ++r) {
    int yr = a - 1 + r;
    bool ok = (yr >= 0) && (yr < 64);
    for (int s = t; s < 1024; s += 512) {          // 2 iters
      int ci = s >> 4, c4 = s & 15;
      u32x4 val = ok ? *reinterpret_cast<const u32x4*>(
                           q_pk + qb + ci * 4096 + yr * 64 + (c4 << 2))
                     : (u32x4)0u;
      unsigned* dst = &rows[ci][r][1 + (c4 << 2)];
      dst[0] = val[0]; dst[1] = val[1]; dst[2] = val[2]; dst[3] = val[3];
    }
  }
  __syncthreads();

  f32x4 acc[4][4];
#pragma unroll
  for (int mt = 0; mt < 4; ++mt)
#pragma unroll
    for (int nt = 0; nt < 4; ++nt) acc[mt][nt] = (f32x4)0.f;

  for (int s8 = 0; s8 < 8; ++s8) {
    FragU ah[4], al[4];
#pragma unroll
    for (int mt = 0; mt < 4; ++mt) {
      long off = ((((long)(v * 8 + s8) * 8 + (coh * 4 + mt)) * 64 + l) * 8);
      ah[mt].u = *reinterpret_cast<const u32x4*>(wAh + off);
      al[mt].u = *reinterpret_cast<const u32x4*>(wAl + off);
    }
#pragma unroll
    for (int nt = 0; nt < 4; ++nt) {
      int p = nt * 16 + (l & 15) + pX;
      int cc0 = (s8 << 3) + ((l >> 4) << 1);
      unsigned u0 = rows[cc0][rA][p], u1 = rows[cc0][rA][p + 1];
      unsigned u2 = rows[cc0][rB][p], u3 = rows[cc0][rB][p + 1];
      unsigned u4 = rows[cc0 + 1][rA][p], u5 = rows[cc0 + 1][rA][p + 1];
      unsigned u6 = rows[cc0 + 1][rB][p], u7 = rows[cc0 + 1][rB][p + 1];
      FragU bh, bl;
      bh.u[0] = (u0 >> 16) | (u1 & 0xFFFF0000u);
      bl.u[0] = (u0 & 0xFFFFu) | (u1 << 16);
      bh.u[1] = (u2 >> 16) | (u3 & 0xFFFF0000u);
      bl.u[1] = (u2 & 0xFFFFu) | (u3 << 16);
      bh.u[2] = (u4 >> 16) | (u5 & 0xFFFF0000u);
      bl.u[2] = (u4 & 0xFFFFu) | (u5 << 16);
      bh.u[3] = (u6 >> 16) | (u7 & 0xFFFF0000u);
      bl.u[3] = (u6 & 0xFFFFu) | (u7 << 16);
#pragma unroll
      for (int mt = 0; mt < 4; ++mt) {
        acc[mt][nt] = __builtin_amdgcn_mfma_f32_16x16x32_bf16(
            ah[mt].h, bh.h, acc[mt][nt], 0, 0, 0);
        acc[mt][nt] = __builtin_amdgcn_mfma_f32_16x16x32_bf16(
            ah[mt].h, bl.h, acc[mt][nt], 0, 0, 0);
        acc[mt][nt] = __builtin_amdgcn_mfma_f32_16x16x32_bf16(
            al[mt].h, bh.h, acc[mt][nt], 0, 0, 0);
      }
    }
  }

#pragma unroll
  for (int mt = 0; mt < 4; ++mt) {
#pragma unroll
    for (int r = 0; r < 4; ++r) {
      int co = ((coh * 4 + mt) << 4) + ((l >> 4) << 2) + r;
      float bias = db2[co];
#pragma unroll
      for (int nt = 0; nt < 4; ++nt) {
        int X = ((nt << 4) + (l & 15)) * 2 + pX;
        float val = fmaxf(acc[mt][nt][r] + bias, 0.f);
        g[((b * 128 + co) * 128 + Y) * 128 + X] = val;
      }
    }
  }
}

// ---------------- convT1 (128->1, 4x4, s2, p1) + sigmoid --------------------
__global__ __launch_bounds__(256) void dconv1_k(
    const float* __restrict__ g, const float* __restrict__ wd1,
    const float* __restrict__ db1, float* __restrict__ rec) {
  int a2 = blockIdx.x, b = blockIdx.y;
  int t = threadIdx.x;
  int w = __builtin_amdgcn_readfirstlane(t >> 6);
  int l = t & 63;
  int xh = w >> 1, pX = w & 1;
  int L = xh * 64 + l;                       // X = 2L + pX
  int kxA = pX ? 0 : 1, kxB = kxA + 2;
  int ixH = L + pX, ixL = L + pX - 1;
  bool okH = ixH < 128, okL = ixL >= 0;
  int yy0 = 2 * a2 - 1;
  bool vy[4];
#pragma unroll
  for (int r = 0; r < 4; ++r) vy[r] = (yy0 + r) >= 0 && (yy0 + r) < 128;

  const float* gb = g + ((long)b * 128) * 16384 + (long)yy0 * 128;
  float acc[4] = {0.f, 0.f, 0.f, 0.f};

  for (int ci = 0; ci < 128; ci += 2) {
    const float* p0 = gb + (long)ci * 16384;
    const float* p1 = p0 + 16384;
    float hi0[4], lo0[4], hi1[4], lo1[4];
#pragma unroll
    for (int r = 0; r < 4; ++r) {
      const float* q0 = p0 + r * 128;
      const float* q1 = p1 + r * 128;
      hi0[r] = (vy[r] && okH) ? q0[ixH] : 0.f;
      lo0[r] = (vy[r] && okL) ? q0[ixL] : 0.f;
      hi1[r] = (vy[r] && okH) ? q1[ixH] : 0.f;
      lo1[r] = (vy[r] && okL) ? q1[ixL] : 0.f;
    }
    const float* wp0 = wd1 + ci * 16;        // wave-uniform -> s_load
    const float* wp1 = wp0 + 16;
#pragma unroll
    for (int j = 0; j < 4; ++j) {
      int kyA = (j + 1) & 1, kyB = kyA + 2;
      int rA = ((j + 1) >> 1) + 1;           // in [1,3]
      float v = acc[j];
      v = fmaf(wp0[kyA * 4 + kxA], hi0[rA], v);
      v = fmaf(wp0[kyA * 4 + kxB], lo0[rA], v);
      v = fmaf(wp0[kyB * 4 + kxA], hi0[rA - 1], v);
      v = fmaf(wp0[kyB * 4 + kxB], lo0[rA - 1], v);
      v = fmaf(wp1[kyA * 4 + kxA], hi1[rA], v);
      v = fmaf(wp1[kyA * 4 + kxB], lo1[rA], v);
      v = fmaf(wp1[kyB * 4 + kxA], hi1[rA - 1], v);
      v = fmaf(wp1[kyB * 4 + kxB], lo1[rA - 1], v);
      acc[j] = v;
    }
  }
  float bb = db1[0];
#pragma unroll
  for (int j = 0; j < 4; ++j) {
    float v = acc[j] + bb;
    v = 1.f / (1.f + __expf(-v));
    rec[((b * 256 + 4 * a2 + j) * 256) + 2 * L + pX] = v;
  }
}

// ---------------------------------------------------------------------------
extern "C" void kernel_launch(void* const* d_in, const int* in_sizes, int n_in,
                              void* d_out, int out_size, void* d_ws, size_t ws_size,
                              hipStream_t stream) {
  const float* x      = (const float*)d_in[0];
  const float* enc_w1 = (const float*)d_in[1];
  const float* enc_b1 = (const float*)d_in[2];
  const float* enc_w2 = (const float*)d_in[3];
  const float* enc_b2 = (const float*)d_in[4];
  const float* cb     = (const float*)d_in[5];
  const float* dec_w2 = (const float*)d_in[6];
  const float* dec_b2 = (const float*)d_in[7];
  const float* dec_w1 = (const float*)d_in[8];
  const float* dec_b1 = (const float*)d_in[9];

  float* out = (float*)d_out;
  float* ws  = (float*)d_ws;
  ushort_t* wCh  = (ushort_t*)ws;                   // 131072 ushort = 65536 f
  ushort_t* wCl  = (ushort_t*)(ws + 65536);
  ushort_t* wAh  = (ushort_t*)(ws + 131072);
  ushort_t* wAl  = (ushort_t*)(ws + 196608);
  ushort_t* cbFh = (ushort_t*)(ws + 262144);        // 32768 ushort = 16384 f
  ushort_t* cbFl = (ushort_t*)(ws + 278528);
  float* csqF = ws + 294912;                        // 8192 f
  float* dyn  = ws + 303104;                        // chunk buffers

  // Per-image: h_pk = 2,097,152 u32 (g f32 aliases), z/q_pk = 262,144.
  const size_t PER_IMG = 2097152 + 262144;                   // 2,359,296 elems
  size_t avail = (ws_size / 4 > 303104 + 64) ? ws_size / 4 - 303104 - 64 : 0;
  int CB = 32;
  while (CB > 1 && (size_t)CB * PER_IMG > avail) CB >>= 1;

  zero_loss_k<<<dim3(1), 64, 0, stream>>>(out);
  repackA2_k<<<dim3(512), 256, 0, stream>>>(enc_w2, wCh, wCl);
  repackA_k<<<dim3(512), 256, 0, stream>>>(dec_w2, wAh, wAl);
  repackCB_k<<<dim3(128), 256, 0, stream>>>(cb, cbFh, cbFl);
  csqF_k<<<dim3(32), 256, 0, stream>>>(cb, csqF);

  for (int b0 = 0; b0 < 32; b0 += CB) {
    unsigned* hp = (unsigned*)dyn;                    // CB*2097152 (g aliases)
    float* zq = dyn + (size_t)CB * 2097152;           // CB*262144 (q_pk aliases)
    conv1_k<<<dim3(128, CB), 128, 0, stream>>>(
        x + (size_t)b0 * 65536, enc_w1, enc_b1, hp);
    conv2_k<<<dim3(32, CB), 512, 0, stream>>>(hp, wCh, wCl, enc_b2, zq);
    vq_k<<<dim3(CB * 64), 256, 0, stream>>>(
        zq, cb, cbFh, cbFl, csqF, (unsigned int*)zq, out, b0 * 4096);
    dconv2_k<<<dim3(64, CB), 512, 0, stream>>>(
        (const unsigned int*)zq, wAh, wAl, dec_b2, (float*)dyn /*g*/);
    dconv1_k<<<dim3(64, CB), 256, 0, stream>>>(
        (float*)dyn /*g*/, dec_w1, dec_b1, out + REC_OFF + (size_t)b0 * 65536);
  }
}